// Round 1
// baseline (2425.454 us; speedup 1.0000x reference)
//
#include <hip/hip_runtime.h>

#define N_NODES   50000
#define N_EDGES   800000
#define IN_DIM    128
#define HID_DIM   256
#define OUT_DIM   64
#define N_CLASSES 40

// ---------------- degree / normalization ----------------

__global__ void k_deg_count(const int* __restrict__ dst, int* __restrict__ degi) {
    int e = blockIdx.x * 256 + threadIdx.x;
    if (e < N_EDGES) atomicAdd(&degi[dst[e]], 1);
}

__global__ void k_dinv(const int* __restrict__ degi, float* __restrict__ dinv) {
    int v = blockIdx.x * 256 + threadIdx.x;
    if (v < N_NODES) dinv[v] = rsqrtf((float)(degi[v] + 1));
}

// ---------------- exclusive scan (3-pass) ----------------

__global__ void k_scan_bsum(const int* __restrict__ vals, int n, int* __restrict__ bsum) {
    __shared__ int sm[256];
    int t = threadIdx.x, i = blockIdx.x * 256 + t;
    sm[t] = (i < n) ? vals[i] : 0;
    __syncthreads();
    for (int s = 128; s > 0; s >>= 1) {
        if (t < s) sm[t] += sm[t + s];
        __syncthreads();
    }
    if (t == 0) bsum[blockIdx.x] = sm[0];
}

__global__ void k_scan_bscan(int* __restrict__ bsum, int nb) {
    __shared__ int sm[256];
    int t = threadIdx.x;
    int orig = (t < nb) ? bsum[t] : 0;
    sm[t] = orig;
    __syncthreads();
    for (int off = 1; off < 256; off <<= 1) {
        int v = (t >= off) ? sm[t - off] : 0;
        __syncthreads();
        sm[t] += v;
        __syncthreads();
    }
    if (t < nb) bsum[t] = sm[t] - orig;  // exclusive
}

__global__ void k_scan_final(const int* __restrict__ vals, int n,
                             const int* __restrict__ bscan, int* __restrict__ out) {
    __shared__ int sm[256];
    int t = threadIdx.x, i = blockIdx.x * 256 + t;
    int orig = (i < n) ? vals[i] : 0;
    sm[t] = orig;
    __syncthreads();
    for (int off = 1; off < 256; off <<= 1) {
        int v = (t >= off) ? sm[t - off] : 0;
        __syncthreads();
        sm[t] += v;
        __syncthreads();
    }
    int excl = sm[t] - orig + bscan[blockIdx.x];
    if (i < n) out[i] = excl;
    if (i == n - 1) out[n] = excl + orig;  // total edge count
}

__global__ void k_csr_fill(const int* __restrict__ src, const int* __restrict__ dst,
                           const int* __restrict__ csr_off, int* __restrict__ cursor,
                           int* __restrict__ csr_src) {
    int e = blockIdx.x * 256 + threadIdx.x;
    if (e < N_EDGES) {
        int d = dst[e];
        int pos = csr_off[d] + atomicAdd(&cursor[d], 1);
        csr_src[pos] = src[e];
    }
}

// ---------------- small utility ----------------

__global__ void k_transpose(const float* __restrict__ in, float* __restrict__ out, int R, int C) {
    int idx = blockIdx.x * 256 + threadIdx.x;
    if (idx < R * C) {
        int r = idx / C, c = idx % C;
        out[c * R + r] = in[idx];
    }
}

__global__ void k_copy_ei(const int* __restrict__ ei, float* __restrict__ out) {
    int j = blockIdx.x * 256 + threadIdx.x;
    if (j < 2 * N_EDGES) out[j] = (float)ei[j];
}

// ---------------- GEMMs ----------------

// h1lin[50000][256] = x[50000][128] @ W1[128][256]; 8 nodes per block
__global__ __launch_bounds__(256) void k_gemm1(const float* __restrict__ x,
                                               const float* __restrict__ W1,
                                               float* __restrict__ out) {
    __shared__ float xs[8][128];
    int t = threadIdx.x;
    int nb = blockIdx.x * 8;
    #pragma unroll
    for (int k = 0; k < 4; k++) {
        int idx = t + k * 256;
        xs[idx >> 7][idx & 127] = x[(size_t)(nb + (idx >> 7)) * IN_DIM + (idx & 127)];
    }
    __syncthreads();
    float acc[8] = {0, 0, 0, 0, 0, 0, 0, 0};
    for (int i = 0; i < IN_DIM; i++) {
        float w = W1[i * HID_DIM + t];
        #pragma unroll
        for (int e = 0; e < 8; e++) acc[e] += xs[e][i] * w;
    }
    #pragma unroll
    for (int e = 0; e < 8; e++) out[(size_t)(nb + e) * HID_DIM + t] = acc[e];
}

// h2lin[50000][64] = h1[50000][256] @ W2[256][64]; 16 nodes per block (4 groups x 4)
__global__ __launch_bounds__(256) void k_gemm2(const float* __restrict__ h,
                                               const float* __restrict__ W2,
                                               float* __restrict__ out) {
    __shared__ float hs[16][256];
    int t = threadIdx.x;
    int nb = blockIdx.x * 16;
    #pragma unroll
    for (int k = 0; k < 16; k++) {
        int idx = t + k * 256;
        hs[idx >> 8][idx & 255] = h[(size_t)(nb + (idx >> 8)) * HID_DIM + (idx & 255)];
    }
    __syncthreads();
    int col = t & 63, grp = t >> 6;
    float acc[4] = {0, 0, 0, 0};
    for (int i = 0; i < HID_DIM; i++) {
        float w = W2[i * OUT_DIM + col];
        #pragma unroll
        for (int e = 0; e < 4; e++) acc[e] += hs[grp * 4 + e][i] * w;
    }
    #pragma unroll
    for (int e = 0; e < 4; e++) out[(size_t)(nb + grp * 4 + e) * OUT_DIM + col] = acc[e];
}

// ---------------- GCN aggregation (CSR gather) ----------------
// out[v] = dinv[v] * ( h[v]*dinv[v] + sum_{s in N_in(v)} h[s]*dinv[s] ) + bias

template <int DIM, bool RELU>
__global__ void k_aggregate(const float* __restrict__ h, const float* __restrict__ dinv,
                            const int* __restrict__ csr_off, const int* __restrict__ csr_src,
                            const float* __restrict__ bias, float* __restrict__ out) {
    int v = blockIdx.x;
    int c = threadIdx.x;
    float dv = dinv[v];
    float acc = h[(size_t)v * DIM + c] * dv;
    int beg = csr_off[v], end = csr_off[v + 1];
    for (int j = beg; j < end; j++) {
        int s = csr_src[j];
        acc += h[(size_t)s * DIM + c] * dinv[s];
    }
    float r = acc * dv + bias[c];
    if (RELU) r = fmaxf(r, 0.f);
    out[(size_t)v * DIM + c] = r;
}

// ---------------- classifier head ----------------

__global__ void k_logits(const float* __restrict__ f, const float* __restrict__ Wc,
                         const float* __restrict__ bc, float* __restrict__ out) {
    __shared__ float fs[64];
    int v = blockIdx.x, t = threadIdx.x;
    fs[t] = f[(size_t)v * OUT_DIM + t];
    __syncthreads();
    if (t < N_CLASSES) {
        float acc = bc[t];
        for (int i = 0; i < OUT_DIM; i++) acc += fs[i] * Wc[i * N_CLASSES + t];
        out[(size_t)v * N_CLASSES + t] = acc;
    }
}

// ---------------- fused edge MLP ----------------
// per block: 32 edges. ef = [f[src] | f[dst]] (LDS), hidden = relu(ef@Wp1+bp1) (LDS),
// edge_feats = hidden@Wp2+bp2 (global). Weights pre-transposed for per-thread float4 loads.

#define TE 32
__global__ __launch_bounds__(256) void k_edge_mlp(const float* __restrict__ f,
                                                  const int* __restrict__ src,
                                                  const int* __restrict__ dst,
                                                  const float* __restrict__ Wp1t,
                                                  const float* __restrict__ bp1,
                                                  const float* __restrict__ Wp2t,
                                                  const float* __restrict__ bp2,
                                                  float* __restrict__ out) {
    __shared__ float ef[TE][128];   // 16 KB
    __shared__ float hid[TE][256];  // 32 KB
    int t = threadIdx.x;
    int e0 = blockIdx.x * TE;

    // gather: 32 edges x 32 float4s each (16 src + 16 dst)
    #pragma unroll
    for (int k = 0; k < 4; k++) {
        int q = t + k * 256;          // float4 slot 0..1023
        int el = q >> 5;              // local edge
        int seg = q & 31;             // float4 within the 128-float row
        int node = (seg < 16) ? src[e0 + el] : dst[e0 + el];
        float4 val = ((const float4*)f)[(size_t)node * (OUT_DIM / 4) + (seg & 15)];
        ((float4*)ef)[q] = val;
    }
    __syncthreads();

    // layer 1: thread t owns hidden column t for all 32 edges
    float acc[TE];
    #pragma unroll
    for (int e = 0; e < TE; e++) acc[e] = 0.f;
    const float4* w4 = (const float4*)(Wp1t + (size_t)t * 128);
    for (int i4 = 0; i4 < 32; i4++) {
        float4 w = w4[i4];
        #pragma unroll
        for (int e = 0; e < TE; e++) {
            float4 ev = ((const float4*)(&ef[e][0]))[i4];  // LDS broadcast
            acc[e] += ev.x * w.x + ev.y * w.y + ev.z * w.z + ev.w * w.w;
        }
    }
    float b1v = bp1[t];
    #pragma unroll
    for (int e = 0; e < TE; e++) hid[e][t] = fmaxf(acc[e] + b1v, 0.f);
    __syncthreads();

    // layer 2: thread (o = t&63, grp = t>>6) owns output col o for 8 edges
    int o = t & 63, grp = t >> 6;
    float acc2[8] = {0, 0, 0, 0, 0, 0, 0, 0};
    const float4* v4 = (const float4*)(Wp2t + (size_t)o * 256);
    for (int k4 = 0; k4 < 64; k4++) {
        float4 w = v4[k4];
        #pragma unroll
        for (int e = 0; e < 8; e++) {
            float4 hv = ((const float4*)(&hid[grp * 8 + e][0]))[k4];  // LDS broadcast
            acc2[e] += hv.x * w.x + hv.y * w.y + hv.z * w.z + hv.w * w.w;
        }
    }
    float b2v = bp2[o];
    #pragma unroll
    for (int e = 0; e < 8; e++)
        out[(size_t)(e0 + grp * 8 + e) * OUT_DIM + o] = acc2[e] + b2v;
}

// ---------------- launcher ----------------

extern "C" void kernel_launch(void* const* d_in, const int* in_sizes, int n_in,
                              void* d_out, int out_size, void* d_ws, size_t ws_size,
                              hipStream_t stream) {
    const float* x   = (const float*)d_in[0];
    const int*   ei  = (const int*)d_in[1];
    const float* W1  = (const float*)d_in[2];
    const float* b1  = (const float*)d_in[3];
    const float* W2  = (const float*)d_in[4];
    const float* b2  = (const float*)d_in[5];
    const float* Wp1 = (const float*)d_in[6];
    const float* bp1 = (const float*)d_in[7];
    const float* Wp2 = (const float*)d_in[8];
    const float* bp2 = (const float*)d_in[9];
    const float* Wc  = (const float*)d_in[10];
    const float* bc  = (const float*)d_in[11];

    const int* src = ei;
    const int* dst = ei + N_EDGES;

    float* out    = (float*)d_out;
    float* f_out  = out;                                   // [50000,64]
    float* ef_out = out + (size_t)N_NODES * OUT_DIM;       // [800000,64]
    float* lg_out = ef_out + (size_t)N_EDGES * OUT_DIM;    // [50000,40]
    float* ei_out = lg_out + (size_t)N_NODES * N_CLASSES;  // [2,800000] as float

    char* p = (char*)d_ws;
    auto alloc = [&](size_t bytes) -> char* {
        char* r = p;
        p += (bytes + 255) / 256 * 256;
        return r;
    };
    float* h1lin   = (float*)alloc((size_t)N_NODES * HID_DIM * 4);  // 51.2 MB
    float* h1      = (float*)alloc((size_t)N_NODES * HID_DIM * 4);  // 51.2 MB
    int*   degi    = (int*)alloc((size_t)N_NODES * 4);
    float* dinv    = (float*)alloc((size_t)N_NODES * 4);
    int*   csr_off = (int*)alloc((size_t)(N_NODES + 1) * 4);
    int*   cursor  = (int*)alloc((size_t)N_NODES * 4);
    int*   csr_src = (int*)alloc((size_t)N_EDGES * 4);
    int*   bsum    = (int*)alloc(256 * 4);
    float* Wp1t    = (float*)alloc((size_t)IN_DIM * HID_DIM * 4);   // wait: 128x256
    float* Wp2t    = (float*)alloc((size_t)HID_DIM * OUT_DIM * 4);  // 256x64
    float* h2lin   = h1lin;  // reuse: h1lin dead after aggregate1

    const int nbScan = (N_NODES + 255) / 256;  // 196

    hipMemsetAsync(degi, 0, (size_t)N_NODES * 4, stream);
    hipMemsetAsync(cursor, 0, (size_t)N_NODES * 4, stream);

    k_deg_count<<<(N_EDGES + 255) / 256, 256, 0, stream>>>(dst, degi);
    k_dinv<<<nbScan, 256, 0, stream>>>(degi, dinv);
    k_scan_bsum<<<nbScan, 256, 0, stream>>>(degi, N_NODES, bsum);
    k_scan_bscan<<<1, 256, 0, stream>>>(bsum, nbScan);
    k_scan_final<<<nbScan, 256, 0, stream>>>(degi, N_NODES, bsum, csr_off);
    k_csr_fill<<<(N_EDGES + 255) / 256, 256, 0, stream>>>(src, dst, csr_off, cursor, csr_src);

    k_transpose<<<(IN_DIM * HID_DIM + 255) / 256, 256, 0, stream>>>(Wp1, Wp1t, 2 * OUT_DIM, 4 * OUT_DIM);
    k_transpose<<<(HID_DIM * OUT_DIM + 255) / 256, 256, 0, stream>>>(Wp2, Wp2t, 4 * OUT_DIM, OUT_DIM);

    k_gemm1<<<N_NODES / 8, 256, 0, stream>>>(x, W1, h1lin);
    k_aggregate<HID_DIM, true><<<N_NODES, HID_DIM, 0, stream>>>(h1lin, dinv, csr_off, csr_src, b1, h1);
    k_gemm2<<<N_NODES / 16, 256, 0, stream>>>(h1, W2, h2lin);
    k_aggregate<OUT_DIM, false><<<N_NODES, OUT_DIM, 0, stream>>>(h2lin, dinv, csr_off, csr_src, b2, f_out);

    k_logits<<<N_NODES, 64, 0, stream>>>(f_out, Wc, bc, lg_out);
    k_edge_mlp<<<N_EDGES / TE, 256, 0, stream>>>(f_out, src, dst, Wp1t, bp1, Wp2t, bp2, ef_out);
    k_copy_ei<<<(2 * N_EDGES + 255) / 256, 256, 0, stream>>>(ei, ei_out);
}

// Round 2
// 768.933 us; speedup vs baseline: 3.1543x; 3.1543x over previous
//
#include <hip/hip_runtime.h>

#define N_NODES   50000
#define N_EDGES   800000
#define IN_DIM    128
#define HID_DIM   256
#define OUT_DIM   64
#define N_CLASSES 40

typedef __attribute__((ext_vector_type(8))) short short8;
typedef __attribute__((ext_vector_type(4))) float f32x4;

__device__ inline short f2bf(float x) {
    unsigned u = __builtin_bit_cast(unsigned, x);
    unsigned r = (u + 0x7FFFu + ((u >> 16) & 1u)) >> 16;
    return (short)r;
}

// ---------------- degree / normalization ----------------

__global__ void k_deg_count(const int* __restrict__ dst, int* __restrict__ degi) {
    int e = blockIdx.x * 256 + threadIdx.x;
    if (e < N_EDGES) atomicAdd(&degi[dst[e]], 1);
}

__global__ void k_dinv(const int* __restrict__ degi, float* __restrict__ dinv) {
    int v = blockIdx.x * 256 + threadIdx.x;
    if (v < N_NODES) dinv[v] = rsqrtf((float)(degi[v] + 1));
}

// ---------------- exclusive scan (3-pass) ----------------

__global__ void k_scan_bsum(const int* __restrict__ vals, int n, int* __restrict__ bsum) {
    __shared__ int sm[256];
    int t = threadIdx.x, i = blockIdx.x * 256 + t;
    sm[t] = (i < n) ? vals[i] : 0;
    __syncthreads();
    for (int s = 128; s > 0; s >>= 1) {
        if (t < s) sm[t] += sm[t + s];
        __syncthreads();
    }
    if (t == 0) bsum[blockIdx.x] = sm[0];
}

__global__ void k_scan_bscan(int* __restrict__ bsum, int nb) {
    __shared__ int sm[256];
    int t = threadIdx.x;
    int orig = (t < nb) ? bsum[t] : 0;
    sm[t] = orig;
    __syncthreads();
    for (int off = 1; off < 256; off <<= 1) {
        int v = (t >= off) ? sm[t - off] : 0;
        __syncthreads();
        sm[t] += v;
        __syncthreads();
    }
    if (t < nb) bsum[t] = sm[t] - orig;  // exclusive
}

__global__ void k_scan_final(const int* __restrict__ vals, int n,
                             const int* __restrict__ bscan, int* __restrict__ out) {
    __shared__ int sm[256];
    int t = threadIdx.x, i = blockIdx.x * 256 + t;
    int orig = (i < n) ? vals[i] : 0;
    sm[t] = orig;
    __syncthreads();
    for (int off = 1; off < 256; off <<= 1) {
        int v = (t >= off) ? sm[t - off] : 0;
        __syncthreads();
        sm[t] += v;
        __syncthreads();
    }
    int excl = sm[t] - orig + bscan[blockIdx.x];
    if (i < n) out[i] = excl;
    if (i == n - 1) out[n] = excl + orig;
}

__global__ void k_csr_fill(const int* __restrict__ src, const int* __restrict__ dst,
                           const int* __restrict__ csr_off, int* __restrict__ cursor,
                           int* __restrict__ csr_src) {
    int e = blockIdx.x * 256 + threadIdx.x;
    if (e < N_EDGES) {
        int d = dst[e];
        int pos = csr_off[d] + atomicAdd(&cursor[d], 1);
        csr_src[pos] = src[e];
    }
}

// ---------------- weight prep: fp32 [K][N] -> bf16 [N][K] ----------------

__global__ void k_prep_w(const float* __restrict__ Wp1, const float* __restrict__ Wp2,
                         short* __restrict__ Wp1b, short* __restrict__ Wp2b) {
    int i = blockIdx.x * 256 + threadIdx.x;
    if (i < 128 * 256) {  // Wp1: [128][256] -> [256][128]
        int k = i >> 8, n = i & 255;
        Wp1b[n * 128 + k] = f2bf(Wp1[i]);
    }
    if (i < 256 * 64) {   // Wp2: [256][64] -> [64][256]
        int k = i >> 6, n = i & 63;
        Wp2b[n * 256 + k] = f2bf(Wp2[i]);
    }
}

__global__ void k_copy_ei(const int* __restrict__ ei, float* __restrict__ out) {
    int j = blockIdx.x * 256 + threadIdx.x;
    if (j < 2 * N_EDGES) out[j] = (float)ei[j];
}

// ---------------- GEMMs (fp32, unchanged this round) ----------------

__global__ __launch_bounds__(256) void k_gemm1(const float* __restrict__ x,
                                               const float* __restrict__ W1,
                                               float* __restrict__ out) {
    __shared__ float xs[8][128];
    int t = threadIdx.x;
    int nb = blockIdx.x * 8;
    #pragma unroll
    for (int k = 0; k < 4; k++) {
        int idx = t + k * 256;
        xs[idx >> 7][idx & 127] = x[(size_t)(nb + (idx >> 7)) * IN_DIM + (idx & 127)];
    }
    __syncthreads();
    float acc[8] = {0, 0, 0, 0, 0, 0, 0, 0};
    for (int i = 0; i < IN_DIM; i++) {
        float w = W1[i * HID_DIM + t];
        #pragma unroll
        for (int e = 0; e < 8; e++) acc[e] += xs[e][i] * w;
    }
    #pragma unroll
    for (int e = 0; e < 8; e++) out[(size_t)(nb + e) * HID_DIM + t] = acc[e];
}

__global__ __launch_bounds__(256) void k_gemm2(const float* __restrict__ h,
                                               const float* __restrict__ W2,
                                               float* __restrict__ out) {
    __shared__ float hs[16][256];
    int t = threadIdx.x;
    int nb = blockIdx.x * 16;
    #pragma unroll
    for (int k = 0; k < 16; k++) {
        int idx = t + k * 256;
        hs[idx >> 8][idx & 255] = h[(size_t)(nb + (idx >> 8)) * HID_DIM + (idx & 255)];
    }
    __syncthreads();
    int col = t & 63, grp = t >> 6;
    float acc[4] = {0, 0, 0, 0};
    for (int i = 0; i < HID_DIM; i++) {
        float w = W2[i * OUT_DIM + col];
        #pragma unroll
        for (int e = 0; e < 4; e++) acc[e] += hs[grp * 4 + e][i] * w;
    }
    #pragma unroll
    for (int e = 0; e < 4; e++) out[(size_t)(nb + grp * 4 + e) * OUT_DIM + col] = acc[e];
}

// ---------------- GCN aggregation (CSR gather) ----------------

template <int DIM, bool RELU>
__global__ void k_aggregate(const float* __restrict__ h, const float* __restrict__ dinv,
                            const int* __restrict__ csr_off, const int* __restrict__ csr_src,
                            const float* __restrict__ bias, float* __restrict__ out) {
    int v = blockIdx.x;
    int c = threadIdx.x;
    float dv = dinv[v];
    float acc = h[(size_t)v * DIM + c] * dv;
    int beg = csr_off[v], end = csr_off[v + 1];
    for (int j = beg; j < end; j++) {
        int s = csr_src[j];
        acc += h[(size_t)s * DIM + c] * dinv[s];
    }
    float r = acc * dv + bias[c];
    if (RELU) r = fmaxf(r, 0.f);
    out[(size_t)v * DIM + c] = r;
}

// ---------------- classifier head ----------------

__global__ void k_logits(const float* __restrict__ f, const float* __restrict__ Wc,
                         const float* __restrict__ bc, float* __restrict__ out) {
    __shared__ float fs[64];
    int v = blockIdx.x, t = threadIdx.x;
    fs[t] = f[(size_t)v * OUT_DIM + t];
    __syncthreads();
    if (t < N_CLASSES) {
        float acc = bc[t];
        for (int i = 0; i < OUT_DIM; i++) acc += fs[i] * Wc[i * N_CLASSES + t];
        out[(size_t)v * N_CLASSES + t] = acc;
    }
}

// ---------------- fused edge MLP (bf16 MFMA) ----------------
// Per block: 64 edges, 4 waves.
//   gather f[src]|f[dst] -> ef LDS [64][128] bf16  (XOR-swizzled)
//   L1: wave w owns cols [w*64, w*64+64): 4x4 frags of 16x16, K=128 -> 64 MFMA/wave
//       relu+bias -> hid LDS [64][256] bf16 (swizzled)
//   L2: wave w owns rows [w*16, w*16+16): 1x4 frags, K=256 -> 32 MFMA/wave -> fp32 out
// Fragment layout (mfma_f32_16x16x32_bf16): A/B lane holds 8 contiguous bf16 along K
// at row/col = lane&15, k = (lane>>4)*8; C/D col=lane&15, row=(lane>>4)*4+reg [m89].

__global__ __launch_bounds__(256, 3) void k_edge_mlp_mfma(
        const float* __restrict__ f,
        const int* __restrict__ src, const int* __restrict__ dst,
        const short* __restrict__ Wp1b, const float* __restrict__ bp1,
        const short* __restrict__ Wp2b, const float* __restrict__ bp2,
        float* __restrict__ out) {
    __shared__ short ef_s[64 * 128];   // 16 KB, row stride 256 B
    __shared__ short hid_s[64 * 256];  // 32 KB, row stride 512 B

    const int t = threadIdx.x;
    const int e0 = blockIdx.x * 64;
    const int lane = t & 63, wv = t >> 6;
    const int lr = lane & 15, lg = lane >> 4;

    // ---- gather: 64 edges x 128 floats = 2048 float4 slots ----
    #pragma unroll
    for (int i = 0; i < 8; i++) {
        int q = t + i * 256;
        int el = q >> 5;           // local edge
        int seg = q & 31;          // float4 within row (0..15 src, 16..31 dst)
        int node = (seg < 16) ? src[e0 + el] : dst[e0 + el];
        float4 v = ((const float4*)f)[(size_t)node * (OUT_DIM / 4) + (seg & 15)];
        ushort4 u;
        u.x = (unsigned short)f2bf(v.x);
        u.y = (unsigned short)f2bf(v.y);
        u.z = (unsigned short)f2bf(v.z);
        u.w = (unsigned short)f2bf(v.w);
        int boff = (el * 256 + seg * 8) ^ ((el & 7) << 4);
        *(ushort4*)((char*)ef_s + boff) = u;
    }
    __syncthreads();

    // ---- layer 1 ----
    {
        short8 Bf[4][4];
        float bb1[4];
        #pragma unroll
        for (int nj = 0; nj < 4; nj++) {
            int ncol = wv * 64 + nj * 16 + lr;
            bb1[nj] = bp1[ncol];
            #pragma unroll
            for (int k = 0; k < 4; k++)
                Bf[nj][k] = *(const short8*)(Wp1b + ncol * 128 + k * 32 + lg * 8);
        }
        #pragma unroll
        for (int mi = 0; mi < 4; mi++) {
            short8 Af[4];
            int arow = mi * 16 + lr;
            #pragma unroll
            for (int k = 0; k < 4; k++) {
                int boff = (arow * 256 + k * 64 + lg * 16) ^ ((arow & 7) << 4);
                Af[k] = *(const short8*)((char*)ef_s + boff);
            }
            #pragma unroll
            for (int nj = 0; nj < 4; nj++) {
                f32x4 acc = {0.f, 0.f, 0.f, 0.f};
                #pragma unroll
                for (int k = 0; k < 4; k++)
                    acc = __builtin_amdgcn_mfma_f32_16x16x32_bf16(Af[k], Bf[nj][k], acc, 0, 0, 0);
                int col = wv * 64 + nj * 16 + lr;
                #pragma unroll
                for (int r = 0; r < 4; r++) {
                    int rowL = mi * 16 + lg * 4 + r;
                    float v = fmaxf(acc[r] + bb1[nj], 0.f);
                    int boff = (rowL * 512 + col * 2) ^ ((rowL & 7) << 4);
                    *(short*)((char*)hid_s + boff) = f2bf(v);
                }
            }
        }
    }
    __syncthreads();

    // ---- layer 2 ----
    {
        short8 A2[8];
        int arow = wv * 16 + lr;
        #pragma unroll
        for (int k = 0; k < 8; k++) {
            int boff = (arow * 512 + k * 64 + lg * 16) ^ ((arow & 7) << 4);
            A2[k] = *(const short8*)((char*)hid_s + boff);
        }
        #pragma unroll
        for (int nj = 0; nj < 4; nj++) {
            int ncol = nj * 16 + lr;
            float bb2 = bp2[ncol];
            f32x4 acc = {0.f, 0.f, 0.f, 0.f};
            #pragma unroll
            for (int k = 0; k < 8; k++) {
                short8 B2 = *(const short8*)(Wp2b + ncol * 256 + k * 32 + lg * 8);
                acc = __builtin_amdgcn_mfma_f32_16x16x32_bf16(A2[k], B2, acc, 0, 0, 0);
            }
            #pragma unroll
            for (int r = 0; r < 4; r++) {
                int rowL = wv * 16 + lg * 4 + r;
                out[(size_t)(e0 + rowL) * OUT_DIM + ncol] = acc[r] + bb2;
            }
        }
    }
}

// ---------------- launcher ----------------

extern "C" void kernel_launch(void* const* d_in, const int* in_sizes, int n_in,
                              void* d_out, int out_size, void* d_ws, size_t ws_size,
                              hipStream_t stream) {
    const float* x   = (const float*)d_in[0];
    const int*   ei  = (const int*)d_in[1];
    const float* W1  = (const float*)d_in[2];
    const float* b1  = (const float*)d_in[3];
    const float* W2  = (const float*)d_in[4];
    const float* b2  = (const float*)d_in[5];
    const float* Wp1 = (const float*)d_in[6];
    const float* bp1 = (const float*)d_in[7];
    const float* Wp2 = (const float*)d_in[8];
    const float* bp2 = (const float*)d_in[9];
    const float* Wc  = (const float*)d_in[10];
    const float* bc  = (const float*)d_in[11];

    const int* src = ei;
    const int* dst = ei + N_EDGES;

    float* out    = (float*)d_out;
    float* f_out  = out;                                   // [50000,64]
    float* ef_out = out + (size_t)N_NODES * OUT_DIM;       // [800000,64]
    float* lg_out = ef_out + (size_t)N_EDGES * OUT_DIM;    // [50000,40]
    float* ei_out = lg_out + (size_t)N_NODES * N_CLASSES;  // [2,800000] as float

    char* p = (char*)d_ws;
    auto alloc = [&](size_t bytes) -> char* {
        char* r = p;
        p += (bytes + 255) / 256 * 256;
        return r;
    };
    float* h1lin   = (float*)alloc((size_t)N_NODES * HID_DIM * 4);
    float* h1      = (float*)alloc((size_t)N_NODES * HID_DIM * 4);
    int*   degi    = (int*)alloc((size_t)N_NODES * 4);
    float* dinv    = (float*)alloc((size_t)N_NODES * 4);
    int*   csr_off = (int*)alloc((size_t)(N_NODES + 1) * 4);
    int*   cursor  = (int*)alloc((size_t)N_NODES * 4);
    int*   csr_src = (int*)alloc((size_t)N_EDGES * 4);
    int*   bsum    = (int*)alloc(256 * 4);
    short* Wp1b    = (short*)alloc((size_t)128 * 256 * 2);
    short* Wp2b    = (short*)alloc((size_t)256 * 64 * 2);
    float* h2lin   = h1lin;  // reuse: h1lin dead after aggregate1

    const int nbScan = (N_NODES + 255) / 256;  // 196

    hipMemsetAsync(degi, 0, (size_t)N_NODES * 4, stream);
    hipMemsetAsync(cursor, 0, (size_t)N_NODES * 4, stream);

    k_deg_count<<<(N_EDGES + 255) / 256, 256, 0, stream>>>(dst, degi);
    k_dinv<<<nbScan, 256, 0, stream>>>(degi, dinv);
    k_scan_bsum<<<nbScan, 256, 0, stream>>>(degi, N_NODES, bsum);
    k_scan_bscan<<<1, 256, 0, stream>>>(bsum, nbScan);
    k_scan_final<<<nbScan, 256, 0, stream>>>(degi, N_NODES, bsum, csr_off);
    k_csr_fill<<<(N_EDGES + 255) / 256, 256, 0, stream>>>(src, dst, csr_off, cursor, csr_src);

    k_prep_w<<<128, 256, 0, stream>>>(Wp1, Wp2, Wp1b, Wp2b);

    k_gemm1<<<N_NODES / 8, 256, 0, stream>>>(x, W1, h1lin);
    k_aggregate<HID_DIM, true><<<N_NODES, HID_DIM, 0, stream>>>(h1lin, dinv, csr_off, csr_src, b1, h1);
    k_gemm2<<<N_NODES / 16, 256, 0, stream>>>(h1, W2, h2lin);
    k_aggregate<OUT_DIM, false><<<N_NODES, OUT_DIM, 0, stream>>>(h2lin, dinv, csr_off, csr_src, b2, f_out);

    k_logits<<<N_NODES, 64, 0, stream>>>(f_out, Wc, bc, lg_out);
    k_edge_mlp_mfma<<<N_EDGES / 64, 256, 0, stream>>>(f_out, src, dst, Wp1b, bp1, Wp2b, bp2, ef_out);
    k_copy_ei<<<(2 * N_EDGES + 255) / 256, 256, 0, stream>>>(ei, ei_out);
}